// Round 2
// baseline (360.689 us; speedup 1.0000x reference)
//
#include <hip/hip_runtime.h>

typedef __attribute__((ext_vector_type(8))) short bf16x8;
typedef __attribute__((ext_vector_type(4))) short bf16x4;
typedef __attribute__((ext_vector_type(4))) float f32x4;
typedef __attribute__((ext_vector_type(4))) unsigned short u16x4;

#define MFMA16(a, b, c) __builtin_amdgcn_mfma_f32_16x16x32_bf16((a), (b), (c), 0, 0, 0)
#define MFMA16K16(a, b, c) __builtin_amdgcn_mfma_f32_16x16x16bf16_1k((a), (b), (c), 0, 0, 0)

__device__ __forceinline__ unsigned short f2bf(float f) {
    union { float f; unsigned int u; } x; x.f = f;
    unsigned int r = x.u + 0x7FFFu + ((x.u >> 16) & 1u);
    return (unsigned short)(r >> 16);
}
__device__ __forceinline__ unsigned int fbits(float f) {
    union { float f; unsigned int u; } x; x.f = f;
    return x.u;
}
__device__ __forceinline__ void gload_lds16(const void* g, void* l) {
    __builtin_amdgcn_global_load_lds(
        (const __attribute__((address_space(1))) unsigned int*)g,
        (__attribute__((address_space(3))) unsigned int*)l,
        16, 0, 0);
}

// ---- x (fp32) -> bf16 cast; also zero-fills the attention partial buffers ----
__global__ void cast_x(const float* __restrict__ in, unsigned short* __restrict__ hi,
                       int n, float4* __restrict__ zptr, int zn) {
    int idx = blockIdx.x * blockDim.x + threadIdx.x;
    int i = idx * 4;
    if (i < n) {
        float4 v = *(const float4*)(in + i);
        float vv[4] = {v.x, v.y, v.z, v.w};
        u16x4 h;
#pragma unroll
        for (int j = 0; j < 4; ++j) h[j] = f2bf(vv[j]);
        *(u16x4*)(hi + i) = h;
    }
    if (idx < zn) zptr[idx] = (float4){0.f, 0.f, 0.f, 0.f};
}

// ---- transpose fp32 [K][N] -> bf16 [N][K] ----
__global__ void tcast_k(const float* __restrict__ in, unsigned short* __restrict__ out,
                        int K, int N) {
    __shared__ float tile[64][65];
    int n0 = blockIdx.x * 64, k0 = blockIdx.y * 64;
    for (int i = threadIdx.x; i < 4096; i += 256) {
        int r = i >> 6, c = i & 63;
        tile[r][c] = in[(size_t)(k0 + r) * N + n0 + c];
    }
    __syncthreads();
    for (int i = threadIdx.x; i < 4096; i += 256) {
        int r = i >> 6, c = i & 63;
        out[(size_t)(n0 + r) * K + k0 + c] = f2bf(tile[c][r]);
    }
}

// ---- QKV GEMM: BK=64, XOR-swizzled LDS (conflict-free), scatter epilogue ----
__global__ __launch_bounds__(256, 2) void gemm_qkv(
    const unsigned short* __restrict__ A,    // 8192 x 1024
    const unsigned short* __restrict__ Bt,   // 3072 x 1024
    unsigned short* __restrict__ qout, unsigned short* __restrict__ kout,
    unsigned short* __restrict__ vtout) {
    const int K = 1024;
    __shared__ __align__(16) unsigned short sA[128 * 64], sB[128 * 64];
    int tid = threadIdx.x, lane = tid & 63, w = tid >> 6;
    int c = lane & 15, quad = lane >> 4;
    int sw = c & 7;
    int wm = (w >> 1) * 64, wn = (w & 1) * 64;
    int m0 = blockIdx.y * 128, n0 = blockIdx.x * 128;

    f32x4 acc[4][4];
#pragma unroll
    for (int i = 0; i < 4; i++)
#pragma unroll
        for (int j = 0; j < 4; j++) acc[i][j] = (f32x4){0.f, 0.f, 0.f, 0.f};

    for (int kk = 0; kk < K; kk += 64) {
#pragma unroll
        for (int p = 0; p < 4; ++p) {
            int ch = p * 256 + tid;
            int r = ch >> 3;
            int gs = (ch & 7) ^ (r & 7);  // source granule for this dest slot
            gload_lds16(A + (size_t)(m0 + r) * K + kk + gs * 8, &sA[ch * 8]);
            gload_lds16(Bt + (size_t)(n0 + r) * K + kk + gs * 8, &sB[ch * 8]);
        }
        __syncthreads();
#pragma unroll
        for (int ks8 = 0; ks8 < 8; ks8 += 4) {  // two K=32 halves
            bf16x8 af[4], bfr[4];
#pragma unroll
            for (int mt = 0; mt < 4; ++mt)
                af[mt] = *(const bf16x8*)&sA[(wm + mt * 16 + c) * 64 +
                                             ((ks8 + quad) ^ sw) * 8];
#pragma unroll
            for (int nt = 0; nt < 4; ++nt)
                bfr[nt] = *(const bf16x8*)&sB[(wn + nt * 16 + c) * 64 +
                                              ((ks8 + quad) ^ sw) * 8];
#pragma unroll
            for (int mt = 0; mt < 4; ++mt)
#pragma unroll
                for (int nt = 0; nt < 4; ++nt)
                    acc[mt][nt] = MFMA16(af[mt], bfr[nt], acc[mt][nt]);
        }
        __syncthreads();
    }

    const float QSCALE = 0.1803368801111601f;  // log2(e) / sqrt(64)
#pragma unroll
    for (int mt = 0; mt < 4; ++mt) {
#pragma unroll
        for (int nt = 0; nt < 4; ++nt) {
#pragma unroll
            for (int r = 0; r < 4; ++r) {
                int row = m0 + wm + mt * 16 + quad * 4 + r;
                int col = n0 + wn + nt * 16 + c;
                float v = acc[mt][nt][r];
                int which = col >> 10;
                int h = (col >> 6) & 15;
                int d = col & 63;
                int b = row >> 11;
                int t = row & 2047;
                size_t bh_ = (size_t)(b * 16 + h);
                if (which == 0)
                    qout[(bh_ * 2048 + t) * 64 + d] = f2bf(v * QSCALE);
                else if (which == 1)
                    kout[(bh_ * 2048 + t) * 64 + d] = f2bf(v);
                else
                    vtout[(bh_ * 64 + d) * 2048 + t] = f2bf(v);
            }
        }
    }
}

// ---- output GEMM: BK=64 swizzled, fp32 store ----
__global__ __launch_bounds__(256, 2) void gemm2_bt(
    const unsigned short* __restrict__ A,    // 8192 x 1024 bf16
    const unsigned short* __restrict__ Bt,   // 1024 x 1024 bf16
    float* __restrict__ out) {
    const int K = 1024, N = 1024;
    __shared__ __align__(16) unsigned short sA[128 * 64], sB[128 * 64];
    int tid = threadIdx.x, lane = tid & 63, w = tid >> 6;
    int c = lane & 15, quad = lane >> 4;
    int sw = c & 7;
    int wm = (w >> 1) * 64, wn = (w & 1) * 64;
    int m0 = blockIdx.y * 128, n0 = blockIdx.x * 128;

    f32x4 acc[4][4];
#pragma unroll
    for (int i = 0; i < 4; i++)
#pragma unroll
        for (int j = 0; j < 4; j++) acc[i][j] = (f32x4){0.f, 0.f, 0.f, 0.f};

    for (int kk = 0; kk < K; kk += 64) {
#pragma unroll
        for (int p = 0; p < 4; ++p) {
            int ch = p * 256 + tid;
            int r = ch >> 3;
            int gs = (ch & 7) ^ (r & 7);
            gload_lds16(A + (size_t)(m0 + r) * K + kk + gs * 8, &sA[ch * 8]);
            gload_lds16(Bt + (size_t)(n0 + r) * K + kk + gs * 8, &sB[ch * 8]);
        }
        __syncthreads();
#pragma unroll
        for (int ks8 = 0; ks8 < 8; ks8 += 4) {
            bf16x8 af[4], bfr[4];
#pragma unroll
            for (int mt = 0; mt < 4; ++mt)
                af[mt] = *(const bf16x8*)&sA[(wm + mt * 16 + c) * 64 +
                                             ((ks8 + quad) ^ sw) * 8];
#pragma unroll
            for (int nt = 0; nt < 4; ++nt)
                bfr[nt] = *(const bf16x8*)&sB[(wn + nt * 16 + c) * 64 +
                                              ((ks8 + quad) ^ sw) * 8];
#pragma unroll
            for (int mt = 0; mt < 4; ++mt)
#pragma unroll
                for (int nt = 0; nt < 4; ++nt)
                    acc[mt][nt] = MFMA16(af[mt], bfr[nt], acc[mt][nt]);
        }
        __syncthreads();
    }

#pragma unroll
    for (int mt = 0; mt < 4; ++mt)
#pragma unroll
        for (int nt = 0; nt < 4; ++nt)
#pragma unroll
            for (int r = 0; r < 4; ++r) {
                int row = m0 + wm + mt * 16 + quad * 4 + r;
                int col = n0 + wn + nt * 16 + c;
                out[(size_t)row * N + col] = acc[mt][nt][r];
            }
}

// ---- causal flash attention: S^T/O^T, P in regs, NO-MAX softmax ----
// v3: critical-path halving + backfill. No-max softmax => partial flash
// states are PURELY ADDITIVE (O = O_a + O_b, l = l_a + l_b): long jobs
// (jt>=8, 18..32 tiles) split into two (jt+1)-tile key-range pieces that
// atomicAdd fp32 partials into scratch (carved from d_out); merge_k
// normalizes. Short jobs (jt<8) keep the direct bf16 path. 1536 blocks,
// longest-first order -> 512 short jobs backfill the tail.
#define SSTR 72
__device__ const int JOB_ORDER[24] = {7, 15, 23, 14, 22, 6,  13, 21, 12, 20, 5,  11,
                                      19, 10, 18, 4,  9,  17, 8,  16, 3,  2,  1,  0};

__global__ __launch_bounds__(256, 4) void attn_k(
    const unsigned short* __restrict__ q,
    const unsigned short* __restrict__ k,
    const unsigned short* __restrict__ vt,
    unsigned short* __restrict__ ctx,
    float* __restrict__ op, float* __restrict__ lbuf) {
    const int T = 2048, D = 64;
    __shared__ __align__(16) unsigned short sK[2][64 * SSTR];  // [buf][key][d]
    __shared__ __align__(16) unsigned short sV[2][64 * SSTR];  // [buf][d][key]

    int tid = threadIdx.x, lane = tid & 63, w = tid >> 6;
    int c = lane & 15, quad = lane >> 4;

    // job decode: rank (longest-first) x bh
    int rank = blockIdx.x >> 6, bh = blockIdx.x & 63;
    int t = JOB_ORDER[rank];
    int jt, kt0, nkt;
    bool split, has_diag;
    if (t < 8)        { jt = t;     kt0 = 0;      nkt = 2 * t + 2; split = false; has_diag = true; }
    else if (t < 16)  { jt = t;     kt0 = 0;      nkt = jt + 1;    split = true;  has_diag = false; }
    else              { jt = t - 8; kt0 = jt + 1; nkt = jt + 1;    split = true;  has_diag = true; }
    int kt_end = kt0 + nkt;
    int b = bh >> 4, hh = bh & 15;

    const unsigned short* qh = q + (size_t)bh * T * D;
    const unsigned short* kh = k + (size_t)bh * T * D;
    const unsigned short* vh = vt + (size_t)bh * D * T;

    int dv = tid >> 3, tcv = (tid & 7) * 8;
    int q0 = jt * 128;
    int qloc = w * 16 + c;
    int qrow[2];
    qrow[0] = q0 + qloc;
    qrow[1] = qrow[0] + 64;

    bf16x8 bq[2][2];
#pragma unroll
    for (int g = 0; g < 2; ++g) {
        bq[g][0] = *(const bf16x8*)&qh[(size_t)qrow[g] * D + quad * 8];
        bq[g][1] = *(const bf16x8*)&qh[(size_t)qrow[g] * D + 32 + quad * 8];
    }

    f32x4 o[2][4];
#pragma unroll
    for (int g = 0; g < 2; ++g)
#pragma unroll
        for (int nt = 0; nt < 4; ++nt) o[g][nt] = (f32x4){0.f, 0.f, 0.f, 0.f};
    float l_i[2] = {0.f, 0.f};

    // stage first tile (kt0) into buffer 0
    int kb0 = kt0 * 64;
    bf16x8 kr0 = *(const bf16x8*)&kh[(size_t)(kb0 + lane) * D + w * 8];
    bf16x8 kr1 = *(const bf16x8*)&kh[(size_t)(kb0 + lane) * D + w * 8 + 32];
    bf16x8 vr0 = *(const bf16x8*)&vh[(size_t)dv * T + kb0 + tcv];
    bf16x8 vr1 = *(const bf16x8*)&vh[(size_t)(dv + 32) * T + kb0 + tcv];
    *(bf16x8*)&sK[0][lane * SSTR + w * 8] = kr0;
    *(bf16x8*)&sK[0][lane * SSTR + w * 8 + 32] = kr1;
    *(bf16x8*)&sV[0][dv * SSTR + tcv] = vr0;
    *(bf16x8*)&sV[0][(dv + 32) * SSTR + tcv] = vr1;
    __syncthreads();

    int cur = 0;
    for (int kt = kt0; kt < kt_end; ++kt) {
        int kb = kt * 64;
        if (kt + 1 < kt_end) {  // prefetch next tile into registers
            int kb2 = kb + 64;
            kr0 = *(const bf16x8*)&kh[(size_t)(kb2 + lane) * D + w * 8];
            kr1 = *(const bf16x8*)&kh[(size_t)(kb2 + lane) * D + w * 8 + 32];
            vr0 = *(const bf16x8*)&vh[(size_t)dv * T + kb2 + tcv];
            vr1 = *(const bf16x8*)&vh[(size_t)(dv + 32) * T + kb2 + tcv];
        }
        // last tile of a diag-carrying job is fully masked for group 0
        bool g0_active = !has_diag || (kt != 2 * jt + 1);

        const unsigned short* sKc = sK[cur];
        const unsigned short* sVc = sV[cur];

        // S^T = K · Q^T
        f32x4 st[2][4];
        __builtin_amdgcn_s_setprio(1);
#pragma unroll
        for (int mt = 0; mt < 4; ++mt) {
            bf16x8 ak0 = *(const bf16x8*)&sKc[(mt * 16 + c) * SSTR + quad * 8];
            bf16x8 ak1 = *(const bf16x8*)&sKc[(mt * 16 + c) * SSTR + 32 + quad * 8];
#pragma unroll
            for (int g = 0; g < 2; ++g) {
                f32x4 z = (f32x4){0.f, 0.f, 0.f, 0.f};
                z = MFMA16(ak0, bq[g][0], z);
                z = MFMA16(ak1, bq[g][1], z);
                st[g][mt] = z;
            }
        }
        __builtin_amdgcn_s_setprio(0);

        // p = exp2(s) directly; pack into PV B-fragments (registers)
        bf16x4 pf[2][4];
#pragma unroll
        for (int g = 0; g < 2; ++g) {
            if (g == 0 && !g0_active) continue;
            bool diag = has_diag && (kb == q0 + (g << 6));
            if (diag) {
#pragma unroll
                for (int mt = 0; mt < 4; ++mt)
#pragma unroll
                    for (int r = 0; r < 4; ++r)
                        if (mt * 16 + quad * 4 + r > qloc) st[g][mt][r] = -1.0e30f;
            }
            float rs = 0.f;
#pragma unroll
            for (int mt = 0; mt < 4; ++mt) {
                float p0 = __builtin_exp2f(st[g][mt][0]);
                float p1 = __builtin_exp2f(st[g][mt][1]);
                float p2 = __builtin_exp2f(st[g][mt][2]);
                float p3 = __builtin_exp2f(st[g][mt][3]);
                rs += (p0 + p1) + (p2 + p3);
                unsigned int w0 = __builtin_amdgcn_perm(
                    fbits(p1) + 0x8000u, fbits(p0) + 0x8000u, 0x07060302u);
                unsigned int w1 = __builtin_amdgcn_perm(
                    fbits(p3) + 0x8000u, fbits(p2) + 0x8000u, 0x07060302u);
                uint2 pk; pk.x = w0; pk.y = w1;
                pf[g][mt] = *(bf16x4*)&pk;
            }
            l_i[g] += rs;
        }

        // O^T += V^T · P^T  via 16x16x16 MFMA (B-operand straight from regs)
        __builtin_amdgcn_s_setprio(1);
#pragma unroll
        for (int mt = 0; mt < 4; ++mt) {
#pragma unroll
            for (int nt = 0; nt < 4; ++nt) {
                bf16x4 av = *(const bf16x4*)&sVc[(nt * 16 + c) * SSTR + mt * 16 + quad * 4];
                if (g0_active) o[0][nt] = MFMA16K16(av, pf[0][mt], o[0][nt]);
                o[1][nt] = MFMA16K16(av, pf[1][mt], o[1][nt]);
            }
        }
        __builtin_amdgcn_s_setprio(0);

        if (kt + 1 < kt_end) {  // commit prefetched tile to the other buffer
            int nxt = cur ^ 1;
            *(bf16x8*)&sK[nxt][lane * SSTR + w * 8] = kr0;
            *(bf16x8*)&sK[nxt][lane * SSTR + w * 8 + 32] = kr1;
            *(bf16x8*)&sV[nxt][dv * SSTR + tcv] = vr0;
            *(bf16x8*)&sV[nxt][(dv + 32) * SSTR + tcv] = vr1;
            __syncthreads();
            cur = nxt;
        }
    }

    if (!split) {
        // epilogue: cross-lane l reduction, normalized bf16 store
#pragma unroll
        for (int g = 0; g < 2; ++g) {
            float l = l_i[g];
            l += __shfl_xor(l, 16);
            l += __shfl_xor(l, 32);
            float inv = 1.0f / l;
#pragma unroll
            for (int nt = 0; nt < 4; ++nt) {
                u16x4 ob;
#pragma unroll
                for (int r = 0; r < 4; ++r) ob[r] = f2bf(o[g][nt][r] * inv);
                *(u16x4*)&ctx[(size_t)(b * T + qrow[g]) * 1024 + hh * 64 + nt * 16 + quad * 4] = ob;
            }
        }
    } else {
        // partial epilogue: un-normalized fp32 atomics (exactly 2 adds/address)
        int sidx = bh * 8 + (jt - 8);
#pragma unroll
        for (int g = 0; g < 2; ++g) {
            float l = l_i[g];
            l += __shfl_xor(l, 16);
            l += __shfl_xor(l, 32);
            int rloc = qrow[g] - q0;
            if (quad == 0) atomicAdd(&lbuf[sidx * 128 + rloc], l);
            float* orow = op + ((size_t)sidx * 128 + rloc) * 64;
#pragma unroll
            for (int nt = 0; nt < 4; ++nt)
#pragma unroll
                for (int r = 0; r < 4; ++r)
                    atomicAdd(&orow[nt * 16 + quad * 4 + r], o[g][nt][r]);
        }
    }
}

// ---- normalize split-job partials into ctx ----
__global__ void merge_k(const float* __restrict__ op, const float* __restrict__ lbuf,
                        unsigned short* __restrict__ ctx) {
    int gid = blockIdx.x * 256 + threadIdx.x;  // 512*128*16 = 1,048,576
    int row = gid >> 4, dq = (gid & 15) * 4;
    int sidx = row >> 7, rloc = row & 127;
    int bh = sidx >> 3, jt = 8 + (sidx & 7);
    int b = bh >> 4, hh = bh & 15;
    int tq = jt * 128 + rloc;
    float inv = 1.0f / lbuf[row];
    float4 o = *(const float4*)(op + (size_t)row * 64 + dq);
    u16x4 ob;
    ob[0] = f2bf(o.x * inv);
    ob[1] = f2bf(o.y * inv);
    ob[2] = f2bf(o.z * inv);
    ob[3] = f2bf(o.w * inv);
    *(u16x4*)&ctx[((size_t)(b * 2048 + tq)) * 1024 + hh * 64 + dq] = ob;
}

extern "C" void kernel_launch(void* const* d_in, const int* in_sizes, int n_in,
                              void* d_out, int out_size, void* d_ws, size_t ws_size,
                              hipStream_t stream) {
    const float* x     = (const float*)d_in[0];  // (4,2048,1024) fp32
    const float* w_qkv = (const float*)d_in[1];  // (1024,3072) fp32
    const float* w_out = (const float*)d_in[2];  // (1024,1024) fp32
    float* out = (float*)d_out;                  // (4,2048,1024) fp32

    char* ws = (char*)d_ws;
    unsigned short* wqkvt = (unsigned short*)(ws + 0);          //  6.29 MB
    unsigned short* woutt = (unsigned short*)(ws + 6291456);    //  2.10 MB
    unsigned short* x_bf  = (unsigned short*)(ws + 8388608);    // 16.78 MB
    unsigned short* qb    = (unsigned short*)(ws + 25165824);   // 16.78 MB
    unsigned short* kb    = (unsigned short*)(ws + 41943040);   // 16.78 MB
    unsigned short* vtb   = (unsigned short*)(ws + 58720256);   // 16.78 MB
    unsigned short* ctx   = (unsigned short*)(ws + 8388608);    // reuse x_bf slot

    // attention partial scratch carved from d_out (dead until gemm2 writes it):
    // op: 512 jobs x 128 rows x 64 d fp32 = 16.78 MB; lbuf: 512*128 fp32 = 256 KB
    float* op   = (float*)d_out;
    float* lbuf = (float*)((char*)d_out + 16777216);

    // cast_x also zero-fills op+lbuf (17039360 B = 1064960 float4s)
    cast_x<<<8192, 256, 0, stream>>>(x, x_bf, 8388608, (float4*)d_out, 1064960);
    tcast_k<<<dim3(48, 16), 256, 0, stream>>>(w_qkv, wqkvt, 1024, 3072);
    tcast_k<<<dim3(16, 16), 256, 0, stream>>>(w_out, woutt, 1024, 1024);
    gemm_qkv<<<dim3(24, 64), 256, 0, stream>>>(x_bf, wqkvt, qb, kb, vtb);
    attn_k<<<1536, 256, 0, stream>>>(qb, kb, vtb, ctx, op, lbuf);
    merge_k<<<4096, 256, 0, stream>>>(op, lbuf, ctx);
    gemm2_bt<<<dim3(8, 64), 256, 0, stream>>>(ctx, woutt, out);
}

// Round 3
// 269.523 us; speedup vs baseline: 1.3383x; 1.3383x over previous
//
#include <hip/hip_runtime.h>

typedef __attribute__((ext_vector_type(8))) short bf16x8;
typedef __attribute__((ext_vector_type(4))) short bf16x4;
typedef __attribute__((ext_vector_type(4))) float f32x4;
typedef __attribute__((ext_vector_type(4))) unsigned short u16x4;

#define MFMA16(a, b, c) __builtin_amdgcn_mfma_f32_16x16x32_bf16((a), (b), (c), 0, 0, 0)
#define MFMA16K16(a, b, c) __builtin_amdgcn_mfma_f32_16x16x16bf16_1k((a), (b), (c), 0, 0, 0)

__device__ __forceinline__ unsigned short f2bf(float f) {
    union { float f; unsigned int u; } x; x.f = f;
    unsigned int r = x.u + 0x7FFFu + ((x.u >> 16) & 1u);
    return (unsigned short)(r >> 16);
}
__device__ __forceinline__ unsigned int fbits(float f) {
    union { float f; unsigned int u; } x; x.f = f;
    return x.u;
}
__device__ __forceinline__ void gload_lds16(const void* g, void* l) {
    __builtin_amdgcn_global_load_lds(
        (const __attribute__((address_space(1))) unsigned int*)g,
        (__attribute__((address_space(3))) unsigned int*)l,
        16, 0, 0);
}

// ---- x (fp32) -> bf16 cast ----
__global__ void cast_x(const float* __restrict__ in, unsigned short* __restrict__ hi,
                       int n) {
    int i = (blockIdx.x * blockDim.x + threadIdx.x) * 4;
    if (i >= n) return;
    float4 v = *(const float4*)(in + i);
    float vv[4] = {v.x, v.y, v.z, v.w};
    u16x4 h;
#pragma unroll
    for (int j = 0; j < 4; ++j) h[j] = f2bf(vv[j]);
    *(u16x4*)(hi + i) = h;
}

// ---- transpose fp32 [K][N] -> bf16 [N][K] ----
__global__ void tcast_k(const float* __restrict__ in, unsigned short* __restrict__ out,
                        int K, int N) {
    __shared__ float tile[64][65];
    int n0 = blockIdx.x * 64, k0 = blockIdx.y * 64;
    for (int i = threadIdx.x; i < 4096; i += 256) {
        int r = i >> 6, c = i & 63;
        tile[r][c] = in[(size_t)(k0 + r) * N + n0 + c];
    }
    __syncthreads();
    for (int i = threadIdx.x; i < 4096; i += 256) {
        int r = i >> 6, c = i & 63;
        out[(size_t)(n0 + r) * K + k0 + c] = f2bf(tile[c][r]);
    }
}

// ---- QKV GEMM: BK=64, XOR-swizzled LDS (conflict-free), scatter epilogue ----
__global__ __launch_bounds__(256, 2) void gemm_qkv(
    const unsigned short* __restrict__ A,    // 8192 x 1024
    const unsigned short* __restrict__ Bt,   // 3072 x 1024
    unsigned short* __restrict__ qout, unsigned short* __restrict__ kout,
    unsigned short* __restrict__ vtout) {
    const int K = 1024;
    __shared__ __align__(16) unsigned short sA[128 * 64], sB[128 * 64];
    int tid = threadIdx.x, lane = tid & 63, w = tid >> 6;
    int c = lane & 15, quad = lane >> 4;
    int sw = c & 7;
    int wm = (w >> 1) * 64, wn = (w & 1) * 64;
    int m0 = blockIdx.y * 128, n0 = blockIdx.x * 128;

    f32x4 acc[4][4];
#pragma unroll
    for (int i = 0; i < 4; i++)
#pragma unroll
        for (int j = 0; j < 4; j++) acc[i][j] = (f32x4){0.f, 0.f, 0.f, 0.f};

    for (int kk = 0; kk < K; kk += 64) {
#pragma unroll
        for (int p = 0; p < 4; ++p) {
            int ch = p * 256 + tid;
            int r = ch >> 3;
            int gs = (ch & 7) ^ (r & 7);  // source granule for this dest slot
            gload_lds16(A + (size_t)(m0 + r) * K + kk + gs * 8, &sA[ch * 8]);
            gload_lds16(Bt + (size_t)(n0 + r) * K + kk + gs * 8, &sB[ch * 8]);
        }
        __syncthreads();
#pragma unroll
        for (int ks8 = 0; ks8 < 8; ks8 += 4) {  // two K=32 halves
            bf16x8 af[4], bfr[4];
#pragma unroll
            for (int mt = 0; mt < 4; ++mt)
                af[mt] = *(const bf16x8*)&sA[(wm + mt * 16 + c) * 64 +
                                             ((ks8 + quad) ^ sw) * 8];
#pragma unroll
            for (int nt = 0; nt < 4; ++nt)
                bfr[nt] = *(const bf16x8*)&sB[(wn + nt * 16 + c) * 64 +
                                              ((ks8 + quad) ^ sw) * 8];
#pragma unroll
            for (int mt = 0; mt < 4; ++mt)
#pragma unroll
                for (int nt = 0; nt < 4; ++nt)
                    acc[mt][nt] = MFMA16(af[mt], bfr[nt], acc[mt][nt]);
        }
        __syncthreads();
    }

    const float QSCALE = 0.1803368801111601f;  // log2(e) / sqrt(64)
#pragma unroll
    for (int mt = 0; mt < 4; ++mt) {
#pragma unroll
        for (int nt = 0; nt < 4; ++nt) {
#pragma unroll
            for (int r = 0; r < 4; ++r) {
                int row = m0 + wm + mt * 16 + quad * 4 + r;
                int col = n0 + wn + nt * 16 + c;
                float v = acc[mt][nt][r];
                int which = col >> 10;
                int h = (col >> 6) & 15;
                int d = col & 63;
                int b = row >> 11;
                int t = row & 2047;
                size_t bh_ = (size_t)(b * 16 + h);
                if (which == 0)
                    qout[(bh_ * 2048 + t) * 64 + d] = f2bf(v * QSCALE);
                else if (which == 1)
                    kout[(bh_ * 2048 + t) * 64 + d] = f2bf(v);
                else
                    vtout[(bh_ * 64 + d) * 2048 + t] = f2bf(v);
            }
        }
    }
}

// ---- output GEMM: BK=64 swizzled, fp32 store ----
__global__ __launch_bounds__(256, 2) void gemm2_bt(
    const unsigned short* __restrict__ A,    // 8192 x 1024 bf16
    const unsigned short* __restrict__ Bt,   // 1024 x 1024 bf16
    float* __restrict__ out) {
    const int K = 1024, N = 1024;
    __shared__ __align__(16) unsigned short sA[128 * 64], sB[128 * 64];
    int tid = threadIdx.x, lane = tid & 63, w = tid >> 6;
    int c = lane & 15, quad = lane >> 4;
    int sw = c & 7;
    int wm = (w >> 1) * 64, wn = (w & 1) * 64;
    int m0 = blockIdx.y * 128, n0 = blockIdx.x * 128;

    f32x4 acc[4][4];
#pragma unroll
    for (int i = 0; i < 4; i++)
#pragma unroll
        for (int j = 0; j < 4; j++) acc[i][j] = (f32x4){0.f, 0.f, 0.f, 0.f};

    for (int kk = 0; kk < K; kk += 64) {
#pragma unroll
        for (int p = 0; p < 4; ++p) {
            int ch = p * 256 + tid;
            int r = ch >> 3;
            int gs = (ch & 7) ^ (r & 7);
            gload_lds16(A + (size_t)(m0 + r) * K + kk + gs * 8, &sA[ch * 8]);
            gload_lds16(Bt + (size_t)(n0 + r) * K + kk + gs * 8, &sB[ch * 8]);
        }
        __syncthreads();
#pragma unroll
        for (int ks8 = 0; ks8 < 8; ks8 += 4) {
            bf16x8 af[4], bfr[4];
#pragma unroll
            for (int mt = 0; mt < 4; ++mt)
                af[mt] = *(const bf16x8*)&sA[(wm + mt * 16 + c) * 64 +
                                             ((ks8 + quad) ^ sw) * 8];
#pragma unroll
            for (int nt = 0; nt < 4; ++nt)
                bfr[nt] = *(const bf16x8*)&sB[(wn + nt * 16 + c) * 64 +
                                              ((ks8 + quad) ^ sw) * 8];
#pragma unroll
            for (int mt = 0; mt < 4; ++mt)
#pragma unroll
                for (int nt = 0; nt < 4; ++nt)
                    acc[mt][nt] = MFMA16(af[mt], bfr[nt], acc[mt][nt]);
        }
        __syncthreads();
    }

#pragma unroll
    for (int mt = 0; mt < 4; ++mt)
#pragma unroll
        for (int nt = 0; nt < 4; ++nt)
#pragma unroll
            for (int r = 0; r < 4; ++r) {
                int row = m0 + wm + mt * 16 + quad * 4 + r;
                int col = n0 + wn + nt * 16 + c;
                out[(size_t)row * N + col] = acc[mt][nt][r];
            }
}

// ---- causal flash attention: S^T/O^T, P in regs, NO-MAX softmax ----
// v4: split/backfill scheduling kept (1536 blocks, longest-first), but the
// split-piece epilogue is now ATOMIC-FREE: piece 0 (no-diag) and piece 1
// (diag) write un-normalized fp32 O/l to their OWN scratch slots with plain
// coalesced float4 stores; merge_k adds the two pieces and normalizes.
// op[2][512][128][64] f32 = 33.5 MB lives in d_out (dead until gemm2);
// lbuf[2][512][128] f32 = 512 KB lives in the dead wqkvt region.
#define SSTR 72
__device__ const int JOB_ORDER[24] = {7, 15, 23, 14, 22, 6,  13, 21, 12, 20, 5,  11,
                                      19, 10, 18, 4,  9,  17, 8,  16, 3,  2,  1,  0};

__global__ __launch_bounds__(256, 4) void attn_k(
    const unsigned short* __restrict__ q,
    const unsigned short* __restrict__ k,
    const unsigned short* __restrict__ vt,
    unsigned short* __restrict__ ctx,
    float* __restrict__ op, float* __restrict__ lbuf) {
    const int T = 2048, D = 64;
    __shared__ __align__(16) unsigned short sK[2][64 * SSTR];  // [buf][key][d]
    __shared__ __align__(16) unsigned short sV[2][64 * SSTR];  // [buf][d][key]

    int tid = threadIdx.x, lane = tid & 63, w = tid >> 6;
    int c = lane & 15, quad = lane >> 4;

    // job decode: rank (longest-first) x bh
    int rank = blockIdx.x >> 6, bh = blockIdx.x & 63;
    int t = JOB_ORDER[rank];
    int jt, kt0, nkt;
    bool split, has_diag;
    if (t < 8)        { jt = t;     kt0 = 0;      nkt = 2 * t + 2; split = false; has_diag = true; }
    else if (t < 16)  { jt = t;     kt0 = 0;      nkt = jt + 1;    split = true;  has_diag = false; }
    else              { jt = t - 8; kt0 = jt + 1; nkt = jt + 1;    split = true;  has_diag = true; }
    int kt_end = kt0 + nkt;
    int b = bh >> 4, hh = bh & 15;

    const unsigned short* qh = q + (size_t)bh * T * D;
    const unsigned short* kh = k + (size_t)bh * T * D;
    const unsigned short* vh = vt + (size_t)bh * D * T;

    int dv = tid >> 3, tcv = (tid & 7) * 8;
    int q0 = jt * 128;
    int qloc = w * 16 + c;
    int qrow[2];
    qrow[0] = q0 + qloc;
    qrow[1] = qrow[0] + 64;

    bf16x8 bq[2][2];
#pragma unroll
    for (int g = 0; g < 2; ++g) {
        bq[g][0] = *(const bf16x8*)&qh[(size_t)qrow[g] * D + quad * 8];
        bq[g][1] = *(const bf16x8*)&qh[(size_t)qrow[g] * D + 32 + quad * 8];
    }

    f32x4 o[2][4];
#pragma unroll
    for (int g = 0; g < 2; ++g)
#pragma unroll
        for (int nt = 0; nt < 4; ++nt) o[g][nt] = (f32x4){0.f, 0.f, 0.f, 0.f};
    float l_i[2] = {0.f, 0.f};

    // stage first tile (kt0) into buffer 0
    int kb0 = kt0 * 64;
    bf16x8 kr0 = *(const bf16x8*)&kh[(size_t)(kb0 + lane) * D + w * 8];
    bf16x8 kr1 = *(const bf16x8*)&kh[(size_t)(kb0 + lane) * D + w * 8 + 32];
    bf16x8 vr0 = *(const bf16x8*)&vh[(size_t)dv * T + kb0 + tcv];
    bf16x8 vr1 = *(const bf16x8*)&vh[(size_t)(dv + 32) * T + kb0 + tcv];
    *(bf16x8*)&sK[0][lane * SSTR + w * 8] = kr0;
    *(bf16x8*)&sK[0][lane * SSTR + w * 8 + 32] = kr1;
    *(bf16x8*)&sV[0][dv * SSTR + tcv] = vr0;
    *(bf16x8*)&sV[0][(dv + 32) * SSTR + tcv] = vr1;
    __syncthreads();

    int cur = 0;
    for (int kt = kt0; kt < kt_end; ++kt) {
        int kb = kt * 64;
        if (kt + 1 < kt_end) {  // prefetch next tile into registers
            int kb2 = kb + 64;
            kr0 = *(const bf16x8*)&kh[(size_t)(kb2 + lane) * D + w * 8];
            kr1 = *(const bf16x8*)&kh[(size_t)(kb2 + lane) * D + w * 8 + 32];
            vr0 = *(const bf16x8*)&vh[(size_t)dv * T + kb2 + tcv];
            vr1 = *(const bf16x8*)&vh[(size_t)(dv + 32) * T + kb2 + tcv];
        }
        // last tile of a diag-carrying job is fully masked for group 0
        bool g0_active = !has_diag || (kt != 2 * jt + 1);

        const unsigned short* sKc = sK[cur];
        const unsigned short* sVc = sV[cur];

        // S^T = K · Q^T
        f32x4 st[2][4];
        __builtin_amdgcn_s_setprio(1);
#pragma unroll
        for (int mt = 0; mt < 4; ++mt) {
            bf16x8 ak0 = *(const bf16x8*)&sKc[(mt * 16 + c) * SSTR + quad * 8];
            bf16x8 ak1 = *(const bf16x8*)&sKc[(mt * 16 + c) * SSTR + 32 + quad * 8];
#pragma unroll
            for (int g = 0; g < 2; ++g) {
                f32x4 z = (f32x4){0.f, 0.f, 0.f, 0.f};
                z = MFMA16(ak0, bq[g][0], z);
                z = MFMA16(ak1, bq[g][1], z);
                st[g][mt] = z;
            }
        }
        __builtin_amdgcn_s_setprio(0);

        // p = exp2(s) directly; pack into PV B-fragments (registers)
        bf16x4 pf[2][4];
#pragma unroll
        for (int g = 0; g < 2; ++g) {
            if (g == 0 && !g0_active) continue;
            bool diag = has_diag && (kb == q0 + (g << 6));
            if (diag) {
#pragma unroll
                for (int mt = 0; mt < 4; ++mt)
#pragma unroll
                    for (int r = 0; r < 4; ++r)
                        if (mt * 16 + quad * 4 + r > qloc) st[g][mt][r] = -1.0e30f;
            }
            float rs = 0.f;
#pragma unroll
            for (int mt = 0; mt < 4; ++mt) {
                float p0 = __builtin_exp2f(st[g][mt][0]);
                float p1 = __builtin_exp2f(st[g][mt][1]);
                float p2 = __builtin_exp2f(st[g][mt][2]);
                float p3 = __builtin_exp2f(st[g][mt][3]);
                rs += (p0 + p1) + (p2 + p3);
                unsigned int w0 = __builtin_amdgcn_perm(
                    fbits(p1) + 0x8000u, fbits(p0) + 0x8000u, 0x07060302u);
                unsigned int w1 = __builtin_amdgcn_perm(
                    fbits(p3) + 0x8000u, fbits(p2) + 0x8000u, 0x07060302u);
                uint2 pk; pk.x = w0; pk.y = w1;
                pf[g][mt] = *(bf16x4*)&pk;
            }
            l_i[g] += rs;
        }

        // O^T += V^T · P^T  via 16x16x16 MFMA (B-operand straight from regs)
        __builtin_amdgcn_s_setprio(1);
#pragma unroll
        for (int mt = 0; mt < 4; ++mt) {
#pragma unroll
            for (int nt = 0; nt < 4; ++nt) {
                bf16x4 av = *(const bf16x4*)&sVc[(nt * 16 + c) * SSTR + mt * 16 + quad * 4];
                if (g0_active) o[0][nt] = MFMA16K16(av, pf[0][mt], o[0][nt]);
                o[1][nt] = MFMA16K16(av, pf[1][mt], o[1][nt]);
            }
        }
        __builtin_amdgcn_s_setprio(0);

        if (kt + 1 < kt_end) {  // commit prefetched tile to the other buffer
            int nxt = cur ^ 1;
            *(bf16x8*)&sK[nxt][lane * SSTR + w * 8] = kr0;
            *(bf16x8*)&sK[nxt][lane * SSTR + w * 8 + 32] = kr1;
            *(bf16x8*)&sV[nxt][dv * SSTR + tcv] = vr0;
            *(bf16x8*)&sV[nxt][(dv + 32) * SSTR + tcv] = vr1;
            __syncthreads();
            cur = nxt;
        }
    }

    if (!split) {
        // epilogue: cross-lane l reduction, normalized bf16 store
#pragma unroll
        for (int g = 0; g < 2; ++g) {
            float l = l_i[g];
            l += __shfl_xor(l, 16);
            l += __shfl_xor(l, 32);
            float inv = 1.0f / l;
#pragma unroll
            for (int nt = 0; nt < 4; ++nt) {
                u16x4 ob;
#pragma unroll
                for (int r = 0; r < 4; ++r) ob[r] = f2bf(o[g][nt][r] * inv);
                *(u16x4*)&ctx[(size_t)(b * T + qrow[g]) * 1024 + hh * 64 + nt * 16 + quad * 4] = ob;
            }
        }
    } else {
        // partial epilogue: plain coalesced fp32 stores into this piece's slot
        int piece = has_diag ? 1 : 0;
        int sidx = bh * 8 + (jt - 8);
        size_t base = (size_t)(piece * 512 + sidx) * 128;
#pragma unroll
        for (int g = 0; g < 2; ++g) {
            float l = l_i[g];
            l += __shfl_xor(l, 16);
            l += __shfl_xor(l, 32);
            int rloc = qrow[g] - q0;
            if (quad == 0) lbuf[base + rloc] = l;
            float* orow = op + (base + rloc) * 64;
#pragma unroll
            for (int nt = 0; nt < 4; ++nt)
                *(f32x4*)&orow[nt * 16 + quad * 4] = o[g][nt];
        }
    }
}

// ---- combine the two pieces of each split job, normalize, write bf16 ctx ----
__global__ void merge_k(const float* __restrict__ op, const float* __restrict__ lbuf,
                        unsigned short* __restrict__ ctx) {
    int gid = blockIdx.x * 256 + threadIdx.x;  // 512*128*16 = 1,048,576
    int row = gid >> 4, dq = (gid & 15) * 4;
    int sidx = row >> 7, rloc = row & 127;
    int bh = sidx >> 3, jt = 8 + (sidx & 7);
    int b = bh >> 4, hh = bh & 15;
    int tq = jt * 128 + rloc;
    float inv = 1.0f / (lbuf[row] + lbuf[65536 + row]);
    float4 o0 = *(const float4*)(op + (size_t)row * 64 + dq);
    float4 o1 = *(const float4*)(op + (size_t)(65536 + row) * 64 + dq);
    u16x4 ob;
    ob[0] = f2bf((o0.x + o1.x) * inv);
    ob[1] = f2bf((o0.y + o1.y) * inv);
    ob[2] = f2bf((o0.z + o1.z) * inv);
    ob[3] = f2bf((o0.w + o1.w) * inv);
    *(u16x4*)&ctx[((size_t)(b * 2048 + tq)) * 1024 + hh * 64 + dq] = ob;
}

extern "C" void kernel_launch(void* const* d_in, const int* in_sizes, int n_in,
                              void* d_out, int out_size, void* d_ws, size_t ws_size,
                              hipStream_t stream) {
    const float* x     = (const float*)d_in[0];  // (4,2048,1024) fp32
    const float* w_qkv = (const float*)d_in[1];  // (1024,3072) fp32
    const float* w_out = (const float*)d_in[2];  // (1024,1024) fp32
    float* out = (float*)d_out;                  // (4,2048,1024) fp32

    char* ws = (char*)d_ws;
    unsigned short* wqkvt = (unsigned short*)(ws + 0);          //  6.29 MB
    unsigned short* woutt = (unsigned short*)(ws + 6291456);    //  2.10 MB
    unsigned short* x_bf  = (unsigned short*)(ws + 8388608);    // 16.78 MB
    unsigned short* qb    = (unsigned short*)(ws + 25165824);   // 16.78 MB
    unsigned short* kb    = (unsigned short*)(ws + 41943040);   // 16.78 MB
    unsigned short* vtb   = (unsigned short*)(ws + 58720256);   // 16.78 MB
    unsigned short* ctx   = (unsigned short*)(ws + 8388608);    // reuse x_bf slot

    // split-piece scratch:
    //   op[2][512][128][64] f32 = 33.55 MB -> d_out (dead until gemm2 writes it)
    //   lbuf[2][512][128]  f32 = 512 KB   -> wqkvt slot (dead after gemm_qkv)
    float* op   = (float*)d_out;
    float* lbuf = (float*)ws;

    cast_x<<<8192, 256, 0, stream>>>(x, x_bf, 8388608);
    tcast_k<<<dim3(48, 16), 256, 0, stream>>>(w_qkv, wqkvt, 1024, 3072);
    tcast_k<<<dim3(16, 16), 256, 0, stream>>>(w_out, woutt, 1024, 1024);
    gemm_qkv<<<dim3(24, 64), 256, 0, stream>>>(x_bf, wqkvt, qb, kb, vtb);
    attn_k<<<1536, 256, 0, stream>>>(qb, kb, vtb, ctx, op, lbuf);
    merge_k<<<4096, 256, 0, stream>>>(op, lbuf, ctx);
    gemm2_bt<<<dim3(8, 64), 256, 0, stream>>>(ctx, woutt, out);
}

// Round 4
// 264.574 us; speedup vs baseline: 1.3633x; 1.0187x over previous
//
#include <hip/hip_runtime.h>

typedef __attribute__((ext_vector_type(8))) short bf16x8;
typedef __attribute__((ext_vector_type(4))) short bf16x4;
typedef __attribute__((ext_vector_type(4))) float f32x4;
typedef __attribute__((ext_vector_type(4))) unsigned short u16x4;

#define MFMA16(a, b, c) __builtin_amdgcn_mfma_f32_16x16x32_bf16((a), (b), (c), 0, 0, 0)
#define MFMA16K16(a, b, c) __builtin_amdgcn_mfma_f32_16x16x16bf16_1k((a), (b), (c), 0, 0, 0)

__device__ __forceinline__ unsigned short f2bf(float f) {
    union { float f; unsigned int u; } x; x.f = f;
    unsigned int r = x.u + 0x7FFFu + ((x.u >> 16) & 1u);
    return (unsigned short)(r >> 16);
}
__device__ __forceinline__ unsigned int fbits(float f) {
    union { float f; unsigned int u; } x; x.f = f;
    return x.u;
}
__device__ __forceinline__ void gload_lds16(const void* g, void* l) {
    __builtin_amdgcn_global_load_lds(
        (const __attribute__((address_space(1))) unsigned int*)g,
        (__attribute__((address_space(3))) unsigned int*)l,
        16, 0, 0);
}

// ---- x (fp32) -> bf16 cast ----
__global__ void cast_x(const float* __restrict__ in, unsigned short* __restrict__ hi,
                       int n) {
    int i = (blockIdx.x * blockDim.x + threadIdx.x) * 4;
    if (i >= n) return;
    float4 v = *(const float4*)(in + i);
    float vv[4] = {v.x, v.y, v.z, v.w};
    u16x4 h;
#pragma unroll
    for (int j = 0; j < 4; ++j) h[j] = f2bf(vv[j]);
    *(u16x4*)(hi + i) = h;
}

// ---- transpose fp32 [K][N] -> bf16 [N][K] ----
__global__ void tcast_k(const float* __restrict__ in, unsigned short* __restrict__ out,
                        int K, int N) {
    __shared__ float tile[64][65];
    int n0 = blockIdx.x * 64, k0 = blockIdx.y * 64;
    for (int i = threadIdx.x; i < 4096; i += 256) {
        int r = i >> 6, c = i & 63;
        tile[r][c] = in[(size_t)(k0 + r) * N + n0 + c];
    }
    __syncthreads();
    for (int i = threadIdx.x; i < 4096; i += 256) {
        int r = i >> 6, c = i & 63;
        out[(size_t)(n0 + r) * K + k0 + c] = f2bf(tile[c][r]);
    }
}

// ---- QKV GEMM: BK=64, XOR-swizzled LDS, XCD-chunked swizzle,
//      LDS-staged coalesced epilogue (Q/K row-major, V transposed) ----
__global__ __launch_bounds__(256, 2) void gemm_qkv(
    const unsigned short* __restrict__ A,    // 8192 x 1024
    const unsigned short* __restrict__ Bt,   // 3072 x 1024
    unsigned short* __restrict__ qout, unsigned short* __restrict__ kout,
    unsigned short* __restrict__ vtout) {
    const int K = 1024;
    // union: K-loop uses [0,16384) as sA|sB; epilogue uses [0,17408) as 128x136 tile
    __shared__ __align__(16) unsigned short smem[17408];
    unsigned short* sA = smem;
    unsigned short* sB = smem + 8192;
    int tid = threadIdx.x, lane = tid & 63, w = tid >> 6;
    int c = lane & 15, quad = lane >> 4;
    int sw = c & 7;
    int wm = (w >> 1) * 64, wn = (w & 1) * 64;

    // XCD-chunked swizzle: 1536 wgs, 192/XCD -> each XCD owns 8 contiguous m-rows
    int wg = blockIdx.y * 24 + blockIdx.x;
    int nid = (wg & 7) * 192 + (wg >> 3);
    int m_blk = nid / 24, n_blk = nid - m_blk * 24;
    int m0 = m_blk * 128, n0 = n_blk * 128;

    f32x4 acc[4][4];
#pragma unroll
    for (int i = 0; i < 4; i++)
#pragma unroll
        for (int j = 0; j < 4; j++) acc[i][j] = (f32x4){0.f, 0.f, 0.f, 0.f};

    for (int kk = 0; kk < K; kk += 64) {
#pragma unroll
        for (int p = 0; p < 4; ++p) {
            int ch = p * 256 + tid;
            int r = ch >> 3;
            int gs = (ch & 7) ^ (r & 7);  // source granule for this dest slot
            gload_lds16(A + (size_t)(m0 + r) * K + kk + gs * 8, &sA[ch * 8]);
            gload_lds16(Bt + (size_t)(n0 + r) * K + kk + gs * 8, &sB[ch * 8]);
        }
        __syncthreads();
#pragma unroll
        for (int ks8 = 0; ks8 < 8; ks8 += 4) {  // two K=32 halves
            bf16x8 af[4], bfr[4];
#pragma unroll
            for (int mt = 0; mt < 4; ++mt)
                af[mt] = *(const bf16x8*)&sA[(wm + mt * 16 + c) * 64 +
                                             ((ks8 + quad) ^ sw) * 8];
#pragma unroll
            for (int nt = 0; nt < 4; ++nt)
                bfr[nt] = *(const bf16x8*)&sB[(wn + nt * 16 + c) * 64 +
                                              ((ks8 + quad) ^ sw) * 8];
#pragma unroll
            for (int mt = 0; mt < 4; ++mt)
#pragma unroll
                for (int nt = 0; nt < 4; ++nt)
                    acc[mt][nt] = MFMA16(af[mt], bfr[nt], acc[mt][nt]);
        }
        __syncthreads();
    }

    // ---- epilogue: stage bf16 tile in LDS, then coalesced 16B stores ----
    const float QSCALE = 0.1803368801111601f;  // log2(e) / sqrt(64)
    bool vreg = (n0 >= 2048);
    if (!vreg) {
        float scale = (n0 < 1024) ? QSCALE : 1.0f;
#pragma unroll
        for (int mt = 0; mt < 4; ++mt)
#pragma unroll
            for (int nt = 0; nt < 4; ++nt)
#pragma unroll
                for (int r = 0; r < 4; ++r)
                    smem[(wm + mt * 16 + quad * 4 + r) * 136 + wn + nt * 16 + c] =
                        f2bf(acc[mt][nt][r] * scale);
    } else {  // transposed stage: [n][m]
#pragma unroll
        for (int mt = 0; mt < 4; ++mt)
#pragma unroll
            for (int nt = 0; nt < 4; ++nt)
#pragma unroll
                for (int r = 0; r < 4; ++r)
                    smem[(wn + nt * 16 + c) * 136 + wm + mt * 16 + quad * 4 + r] =
                        f2bf(acc[mt][nt][r]);
    }
    __syncthreads();

    int rr = tid >> 4, cc = tid & 15;
    if (!vreg) {
        int col = n0 + cc * 8;
        int which = col >> 10;               // uniform per block (0=Q, 1=K)
        int h = (col >> 6) & 15, d = col & 63;
        unsigned short* dst = which ? kout : qout;
#pragma unroll
        for (int j = 0; j < 8; ++j) {
            int row = rr + j * 16;
            int grow = m0 + row;
            int b = grow >> 11, t = grow & 2047;
            size_t bh_ = (size_t)(b * 16 + h);
            bf16x8 vv = *(const bf16x8*)&smem[row * 136 + cc * 8];
            *(bf16x8*)&dst[(bh_ * 2048 + t) * 64 + d] = vv;
        }
    } else {
        int grow = m0 + cc * 8;
        int b = grow >> 11, t = grow & 2047;  // whole 8-chunk stays in one b,t-range
#pragma unroll
        for (int j = 0; j < 8; ++j) {
            int nrow = rr + j * 16;
            int col = n0 + nrow;
            int h = (col >> 6) & 15, d = col & 63;
            size_t bh_ = (size_t)(b * 16 + h);
            bf16x8 vv = *(const bf16x8*)&smem[nrow * 136 + cc * 8];
            *(bf16x8*)&vtout[(bh_ * 64 + d) * 2048 + t] = vv;
        }
    }
}

// ---- output GEMM: BK=64 swizzled, XCD-chunked, fp32 store ----
__global__ __launch_bounds__(256, 2) void gemm2_bt(
    const unsigned short* __restrict__ A,    // 8192 x 1024 bf16
    const unsigned short* __restrict__ Bt,   // 1024 x 1024 bf16
    float* __restrict__ out) {
    const int K = 1024, N = 1024;
    __shared__ __align__(16) unsigned short sA[128 * 64], sB[128 * 64];
    int tid = threadIdx.x, lane = tid & 63, w = tid >> 6;
    int c = lane & 15, quad = lane >> 4;
    int sw = c & 7;
    int wm = (w >> 1) * 64, wn = (w & 1) * 64;

    // XCD-chunked swizzle: 512 wgs, 64/XCD -> XCD owns 8 m-rows; A-chunk (2MB)
    // + full B (2MB) fit the 4MB XCD L2.
    int wg = blockIdx.y * 8 + blockIdx.x;
    int nid = (wg & 7) * 64 + (wg >> 3);
    int m_blk = nid >> 3, n_blk = nid & 7;
    int m0 = m_blk * 128, n0 = n_blk * 128;

    f32x4 acc[4][4];
#pragma unroll
    for (int i = 0; i < 4; i++)
#pragma unroll
        for (int j = 0; j < 4; j++) acc[i][j] = (f32x4){0.f, 0.f, 0.f, 0.f};

    for (int kk = 0; kk < K; kk += 64) {
#pragma unroll
        for (int p = 0; p < 4; ++p) {
            int ch = p * 256 + tid;
            int r = ch >> 3;
            int gs = (ch & 7) ^ (r & 7);
            gload_lds16(A + (size_t)(m0 + r) * K + kk + gs * 8, &sA[ch * 8]);
            gload_lds16(Bt + (size_t)(n0 + r) * K + kk + gs * 8, &sB[ch * 8]);
        }
        __syncthreads();
#pragma unroll
        for (int ks8 = 0; ks8 < 8; ks8 += 4) {
            bf16x8 af[4], bfr[4];
#pragma unroll
            for (int mt = 0; mt < 4; ++mt)
                af[mt] = *(const bf16x8*)&sA[(wm + mt * 16 + c) * 64 +
                                             ((ks8 + quad) ^ sw) * 8];
#pragma unroll
            for (int nt = 0; nt < 4; ++nt)
                bfr[nt] = *(const bf16x8*)&sB[(wn + nt * 16 + c) * 64 +
                                              ((ks8 + quad) ^ sw) * 8];
#pragma unroll
            for (int mt = 0; mt < 4; ++mt)
#pragma unroll
                for (int nt = 0; nt < 4; ++nt)
                    acc[mt][nt] = MFMA16(af[mt], bfr[nt], acc[mt][nt]);
        }
        __syncthreads();
    }

#pragma unroll
    for (int mt = 0; mt < 4; ++mt)
#pragma unroll
        for (int nt = 0; nt < 4; ++nt)
#pragma unroll
            for (int r = 0; r < 4; ++r) {
                int row = m0 + wm + mt * 16 + quad * 4 + r;
                int col = n0 + wn + nt * 16 + c;
                out[(size_t)row * N + col] = acc[mt][nt][r];
            }
}

// ---- causal flash attention: S^T/O^T, P in regs, NO-MAX softmax ----
// split/backfill scheduling (1536 blocks, longest-first); split pieces write
// their own fp32 scratch slots (atomic-free); merge_k combines+normalizes.
#define SSTR 72
__device__ const int JOB_ORDER[24] = {7, 15, 23, 14, 22, 6,  13, 21, 12, 20, 5,  11,
                                      19, 10, 18, 4,  9,  17, 8,  16, 3,  2,  1,  0};

__global__ __launch_bounds__(256, 4) void attn_k(
    const unsigned short* __restrict__ q,
    const unsigned short* __restrict__ k,
    const unsigned short* __restrict__ vt,
    unsigned short* __restrict__ ctx,
    float* __restrict__ op, float* __restrict__ lbuf) {
    const int T = 2048, D = 64;
    __shared__ __align__(16) unsigned short sK[2][64 * SSTR];  // [buf][key][d]
    __shared__ __align__(16) unsigned short sV[2][64 * SSTR];  // [buf][d][key]

    int tid = threadIdx.x, lane = tid & 63, w = tid >> 6;
    int c = lane & 15, quad = lane >> 4;

    // job decode: rank (longest-first) x bh
    int rank = blockIdx.x >> 6, bh = blockIdx.x & 63;
    int t = JOB_ORDER[rank];
    int jt, kt0, nkt;
    bool split, has_diag;
    if (t < 8)        { jt = t;     kt0 = 0;      nkt = 2 * t + 2; split = false; has_diag = true; }
    else if (t < 16)  { jt = t;     kt0 = 0;      nkt = jt + 1;    split = true;  has_diag = false; }
    else              { jt = t - 8; kt0 = jt + 1; nkt = jt + 1;    split = true;  has_diag = true; }
    int kt_end = kt0 + nkt;
    int b = bh >> 4, hh = bh & 15;

    const unsigned short* qh = q + (size_t)bh * T * D;
    const unsigned short* kh = k + (size_t)bh * T * D;
    const unsigned short* vh = vt + (size_t)bh * D * T;

    int dv = tid >> 3, tcv = (tid & 7) * 8;
    int q0 = jt * 128;
    int qloc = w * 16 + c;
    int qrow[2];
    qrow[0] = q0 + qloc;
    qrow[1] = qrow[0] + 64;

    bf16x8 bq[2][2];
#pragma unroll
    for (int g = 0; g < 2; ++g) {
        bq[g][0] = *(const bf16x8*)&qh[(size_t)qrow[g] * D + quad * 8];
        bq[g][1] = *(const bf16x8*)&qh[(size_t)qrow[g] * D + 32 + quad * 8];
    }

    f32x4 o[2][4];
#pragma unroll
    for (int g = 0; g < 2; ++g)
#pragma unroll
        for (int nt = 0; nt < 4; ++nt) o[g][nt] = (f32x4){0.f, 0.f, 0.f, 0.f};
    float l_i[2] = {0.f, 0.f};

    // stage first tile (kt0) into buffer 0
    int kb0 = kt0 * 64;
    bf16x8 kr0 = *(const bf16x8*)&kh[(size_t)(kb0 + lane) * D + w * 8];
    bf16x8 kr1 = *(const bf16x8*)&kh[(size_t)(kb0 + lane) * D + w * 8 + 32];
    bf16x8 vr0 = *(const bf16x8*)&vh[(size_t)dv * T + kb0 + tcv];
    bf16x8 vr1 = *(const bf16x8*)&vh[(size_t)(dv + 32) * T + kb0 + tcv];
    *(bf16x8*)&sK[0][lane * SSTR + w * 8] = kr0;
    *(bf16x8*)&sK[0][lane * SSTR + w * 8 + 32] = kr1;
    *(bf16x8*)&sV[0][dv * SSTR + tcv] = vr0;
    *(bf16x8*)&sV[0][(dv + 32) * SSTR + tcv] = vr1;
    __syncthreads();

    int cur = 0;
    for (int kt = kt0; kt < kt_end; ++kt) {
        int kb = kt * 64;
        if (kt + 1 < kt_end) {  // prefetch next tile into registers
            int kb2 = kb + 64;
            kr0 = *(const bf16x8*)&kh[(size_t)(kb2 + lane) * D + w * 8];
            kr1 = *(const bf16x8*)&kh[(size_t)(kb2 + lane) * D + w * 8 + 32];
            vr0 = *(const bf16x8*)&vh[(size_t)dv * T + kb2 + tcv];
            vr1 = *(const bf16x8*)&vh[(size_t)(dv + 32) * T + kb2 + tcv];
        }
        // last tile of a diag-carrying job is fully masked for group 0
        bool g0_active = !has_diag || (kt != 2 * jt + 1);

        const unsigned short* sKc = sK[cur];
        const unsigned short* sVc = sV[cur];

        // S^T = K · Q^T
        f32x4 st[2][4];
        __builtin_amdgcn_s_setprio(1);
#pragma unroll
        for (int mt = 0; mt < 4; ++mt) {
            bf16x8 ak0 = *(const bf16x8*)&sKc[(mt * 16 + c) * SSTR + quad * 8];
            bf16x8 ak1 = *(const bf16x8*)&sKc[(mt * 16 + c) * SSTR + 32 + quad * 8];
#pragma unroll
            for (int g = 0; g < 2; ++g) {
                f32x4 z = (f32x4){0.f, 0.f, 0.f, 0.f};
                z = MFMA16(ak0, bq[g][0], z);
                z = MFMA16(ak1, bq[g][1], z);
                st[g][mt] = z;
            }
        }
        __builtin_amdgcn_s_setprio(0);

        // p = exp2(s) directly; pack into PV B-fragments (registers)
        bf16x4 pf[2][4];
#pragma unroll
        for (int g = 0; g < 2; ++g) {
            if (g == 0 && !g0_active) continue;
            bool diag = has_diag && (kb == q0 + (g << 6));
            if (diag) {
#pragma unroll
                for (int mt = 0; mt < 4; ++mt)
#pragma unroll
                    for (int r = 0; r < 4; ++r)
                        if (mt * 16 + quad * 4 + r > qloc) st[g][mt][r] = -1.0e30f;
            }
            float rs = 0.f;
#pragma unroll
            for (int mt = 0; mt < 4; ++mt) {
                float p0 = __builtin_exp2f(st[g][mt][0]);
                float p1 = __builtin_exp2f(st[g][mt][1]);
                float p2 = __builtin_exp2f(st[g][mt][2]);
                float p3 = __builtin_exp2f(st[g][mt][3]);
                rs += (p0 + p1) + (p2 + p3);
                unsigned int w0 = __builtin_amdgcn_perm(
                    fbits(p1) + 0x8000u, fbits(p0) + 0x8000u, 0x07060302u);
                unsigned int w1 = __builtin_amdgcn_perm(
                    fbits(p3) + 0x8000u, fbits(p2) + 0x8000u, 0x07060302u);
                uint2 pk; pk.x = w0; pk.y = w1;
                pf[g][mt] = *(bf16x4*)&pk;
            }
            l_i[g] += rs;
        }

        // O^T += V^T · P^T  via 16x16x16 MFMA (B-operand straight from regs)
        __builtin_amdgcn_s_setprio(1);
#pragma unroll
        for (int mt = 0; mt < 4; ++mt) {
#pragma unroll
            for (int nt = 0; nt < 4; ++nt) {
                bf16x4 av = *(const bf16x4*)&sVc[(nt * 16 + c) * SSTR + mt * 16 + quad * 4];
                if (g0_active) o[0][nt] = MFMA16K16(av, pf[0][mt], o[0][nt]);
                o[1][nt] = MFMA16K16(av, pf[1][mt], o[1][nt]);
            }
        }
        __builtin_amdgcn_s_setprio(0);

        if (kt + 1 < kt_end) {  // commit prefetched tile to the other buffer
            int nxt = cur ^ 1;
            *(bf16x8*)&sK[nxt][lane * SSTR + w * 8] = kr0;
            *(bf16x8*)&sK[nxt][lane * SSTR + w * 8 + 32] = kr1;
            *(bf16x8*)&sV[nxt][dv * SSTR + tcv] = vr0;
            *(bf16x8*)&sV[nxt][(dv + 32) * SSTR + tcv] = vr1;
            __syncthreads();
            cur = nxt;
        }
    }

    if (!split) {
        // epilogue: cross-lane l reduction, normalized bf16 store
#pragma unroll
        for (int g = 0; g < 2; ++g) {
            float l = l_i[g];
            l += __shfl_xor(l, 16);
            l += __shfl_xor(l, 32);
            float inv = 1.0f / l;
#pragma unroll
            for (int nt = 0; nt < 4; ++nt) {
                u16x4 ob;
#pragma unroll
                for (int r = 0; r < 4; ++r) ob[r] = f2bf(o[g][nt][r] * inv);
                *(u16x4*)&ctx[(size_t)(b * T + qrow[g]) * 1024 + hh * 64 + nt * 16 + quad * 4] = ob;
            }
        }
    } else {
        // partial epilogue: plain coalesced fp32 stores into this piece's slot
        int piece = has_diag ? 1 : 0;
        int sidx = bh * 8 + (jt - 8);
        size_t base = (size_t)(piece * 512 + sidx) * 128;
#pragma unroll
        for (int g = 0; g < 2; ++g) {
            float l = l_i[g];
            l += __shfl_xor(l, 16);
            l += __shfl_xor(l, 32);
            int rloc = qrow[g] - q0;
            if (quad == 0) lbuf[base + rloc] = l;
            float* orow = op + (base + rloc) * 64;
#pragma unroll
            for (int nt = 0; nt < 4; ++nt)
                *(f32x4*)&orow[nt * 16 + quad * 4] = o[g][nt];
        }
    }
}

// ---- combine the two pieces of each split job, normalize, write bf16 ctx ----
__global__ void merge_k(const float* __restrict__ op, const float* __restrict__ lbuf,
                        unsigned short* __restrict__ ctx) {
    int gid = blockIdx.x * 256 + threadIdx.x;  // 512*128*16 = 1,048,576
    int row = gid >> 4, dq = (gid & 15) * 4;
    int sidx = row >> 7, rloc = row & 127;
    int bh = sidx >> 3, jt = 8 + (sidx & 7);
    int b = bh >> 4, hh = bh & 15;
    int tq = jt * 128 + rloc;
    float inv = 1.0f / (lbuf[row] + lbuf[65536 + row]);
    float4 o0 = *(const float4*)(op + (size_t)row * 64 + dq);
    float4 o1 = *(const float4*)(op + (size_t)(65536 + row) * 64 + dq);
    u16x4 ob;
    ob[0] = f2bf((o0.x + o1.x) * inv);
    ob[1] = f2bf((o0.y + o1.y) * inv);
    ob[2] = f2bf((o0.z + o1.z) * inv);
    ob[3] = f2bf((o0.w + o1.w) * inv);
    *(u16x4*)&ctx[((size_t)(b * 2048 + tq)) * 1024 + hh * 64 + dq] = ob;
}

extern "C" void kernel_launch(void* const* d_in, const int* in_sizes, int n_in,
                              void* d_out, int out_size, void* d_ws, size_t ws_size,
                              hipStream_t stream) {
    const float* x     = (const float*)d_in[0];  // (4,2048,1024) fp32
    const float* w_qkv = (const float*)d_in[1];  // (1024,3072) fp32
    const float* w_out = (const float*)d_in[2];  // (1024,1024) fp32
    float* out = (float*)d_out;                  // (4,2048,1024) fp32

    char* ws = (char*)d_ws;
    unsigned short* wqkvt = (unsigned short*)(ws + 0);          //  6.29 MB
    unsigned short* woutt = (unsigned short*)(ws + 6291456);    //  2.10 MB
    unsigned short* x_bf  = (unsigned short*)(ws + 8388608);    // 16.78 MB
    unsigned short* qb    = (unsigned short*)(ws + 25165824);   // 16.78 MB
    unsigned short* kb    = (unsigned short*)(ws + 41943040);   // 16.78 MB
    unsigned short* vtb   = (unsigned short*)(ws + 58720256);   // 16.78 MB
    unsigned short* ctx   = (unsigned short*)(ws + 8388608);    // reuse x_bf slot

    // split-piece scratch:
    //   op[2][512][128][64] f32 = 33.55 MB -> d_out (dead until gemm2 writes it)
    //   lbuf[2][512][128]  f32 = 512 KB   -> wqkvt slot (dead after gemm_qkv)
    float* op   = (float*)d_out;
    float* lbuf = (float*)ws;

    cast_x<<<8192, 256, 0, stream>>>(x, x_bf, 8388608);
    tcast_k<<<dim3(48, 16), 256, 0, stream>>>(w_qkv, wqkvt, 1024, 3072);
    tcast_k<<<dim3(16, 16), 256, 0, stream>>>(w_out, woutt, 1024, 1024);
    gemm_qkv<<<dim3(24, 64), 256, 0, stream>>>(x_bf, wqkvt, qb, kb, vtb);
    attn_k<<<1536, 256, 0, stream>>>(qb, kb, vtb, ctx, op, lbuf);
    merge_k<<<4096, 256, 0, stream>>>(op, lbuf, ctx);
    gemm2_bt<<<dim3(8, 64), 256, 0, stream>>>(ctx, woutt, out);
}

// Round 5
// 252.138 us; speedup vs baseline: 1.4305x; 1.0493x over previous
//
#include <hip/hip_runtime.h>

typedef __attribute__((ext_vector_type(8))) short bf16x8;
typedef __attribute__((ext_vector_type(4))) short bf16x4;
typedef __attribute__((ext_vector_type(4))) float f32x4;
typedef __attribute__((ext_vector_type(4))) unsigned short u16x4;

#define MFMA16(a, b, c) __builtin_amdgcn_mfma_f32_16x16x32_bf16((a), (b), (c), 0, 0, 0)
#define MFMA16K16(a, b, c) __builtin_amdgcn_mfma_f32_16x16x16bf16_1k((a), (b), (c), 0, 0, 0)

__device__ __forceinline__ unsigned short f2bf(float f) {
    union { float f; unsigned int u; } x; x.f = f;
    unsigned int r = x.u + 0x7FFFu + ((x.u >> 16) & 1u);
    return (unsigned short)(r >> 16);
}
__device__ __forceinline__ void gload_lds16(const void* g, void* l) {
    __builtin_amdgcn_global_load_lds(
        (const __attribute__((address_space(1))) unsigned int*)g,
        (__attribute__((address_space(3))) unsigned int*)l,
        16, 0, 0);
}

// ---- x (fp32) -> bf16 cast ----
__global__ void cast_x(const float* __restrict__ in, unsigned short* __restrict__ hi,
                       int n) {
    int i = (blockIdx.x * blockDim.x + threadIdx.x) * 4;
    if (i >= n) return;
    float4 v = *(const float4*)(in + i);
    float vv[4] = {v.x, v.y, v.z, v.w};
    u16x4 h;
#pragma unroll
    for (int j = 0; j < 4; ++j) h[j] = f2bf(vv[j]);
    *(u16x4*)(hi + i) = h;
}

// ---- transpose fp32 [K][N] -> bf16 [N][K] ----
__global__ void tcast_k(const float* __restrict__ in, unsigned short* __restrict__ out,
                        int K, int N) {
    __shared__ float tile[64][65];
    int n0 = blockIdx.x * 64, k0 = blockIdx.y * 64;
    for (int i = threadIdx.x; i < 4096; i += 256) {
        int r = i >> 6, c = i & 63;
        tile[r][c] = in[(size_t)(k0 + r) * N + n0 + c];
    }
    __syncthreads();
    for (int i = threadIdx.x; i < 4096; i += 256) {
        int r = i >> 6, c = i & 63;
        out[(size_t)(n0 + r) * K + k0 + c] = f2bf(tile[c][r]);
    }
}

// ---- QKV GEMM: BK=64, XOR-swizzled LDS, XCD-chunked swizzle,
//      LDS-staged coalesced epilogue (Q/K row-major, V transposed) ----
// Also initializes the attention work-queue counter (dead wqkvt region).
__global__ __launch_bounds__(256, 2) void gemm_qkv(
    const unsigned short* __restrict__ A,    // 8192 x 1024
    const unsigned short* __restrict__ Bt,   // 3072 x 1024
    unsigned short* __restrict__ qout, unsigned short* __restrict__ kout,
    unsigned short* __restrict__ vtout, int* __restrict__ counter) {
    const int K = 1024;
    // union: K-loop uses [0,16384) as sA|sB; epilogue uses [0,17408) as 128x136 tile
    __shared__ __align__(16) unsigned short smem[17408];
    unsigned short* sA = smem;
    unsigned short* sB = smem + 8192;
    int tid = threadIdx.x, lane = tid & 63, w = tid >> 6;
    int c = lane & 15, quad = lane >> 4;
    int sw = c & 7;
    int wm = (w >> 1) * 64, wn = (w & 1) * 64;

    if (tid == 0) *counter = 1024;  // uniform redundant store; done before attn_k

    // XCD-chunked swizzle: 1536 wgs, 192/XCD -> each XCD owns 8 contiguous m-rows
    int wg = blockIdx.y * 24 + blockIdx.x;
    int nid = (wg & 7) * 192 + (wg >> 3);
    int m_blk = nid / 24, n_blk = nid - m_blk * 24;
    int m0 = m_blk * 128, n0 = n_blk * 128;

    f32x4 acc[4][4];
#pragma unroll
    for (int i = 0; i < 4; i++)
#pragma unroll
        for (int j = 0; j < 4; j++) acc[i][j] = (f32x4){0.f, 0.f, 0.f, 0.f};

    for (int kk = 0; kk < K; kk += 64) {
#pragma unroll
        for (int p = 0; p < 4; ++p) {
            int ch = p * 256 + tid;
            int r = ch >> 3;
            int gs = (ch & 7) ^ (r & 7);  // source granule for this dest slot
            gload_lds16(A + (size_t)(m0 + r) * K + kk + gs * 8, &sA[ch * 8]);
            gload_lds16(Bt + (size_t)(n0 + r) * K + kk + gs * 8, &sB[ch * 8]);
        }
        __syncthreads();
#pragma unroll
        for (int ks8 = 0; ks8 < 8; ks8 += 4) {  // two K=32 halves
            bf16x8 af[4], bfr[4];
#pragma unroll
            for (int mt = 0; mt < 4; ++mt)
                af[mt] = *(const bf16x8*)&sA[(wm + mt * 16 + c) * 64 +
                                             ((ks8 + quad) ^ sw) * 8];
#pragma unroll
            for (int nt = 0; nt < 4; ++nt)
                bfr[nt] = *(const bf16x8*)&sB[(wn + nt * 16 + c) * 64 +
                                              ((ks8 + quad) ^ sw) * 8];
#pragma unroll
            for (int mt = 0; mt < 4; ++mt)
#pragma unroll
                for (int nt = 0; nt < 4; ++nt)
                    acc[mt][nt] = MFMA16(af[mt], bfr[nt], acc[mt][nt]);
        }
        __syncthreads();
    }

    // ---- epilogue: stage bf16 tile in LDS, then coalesced 16B stores ----
    const float QSCALE = 0.1803368801111601f;  // log2(e) / sqrt(64)
    bool vreg = (n0 >= 2048);
    if (!vreg) {
        float scale = (n0 < 1024) ? QSCALE : 1.0f;
#pragma unroll
        for (int mt = 0; mt < 4; ++mt)
#pragma unroll
            for (int nt = 0; nt < 4; ++nt)
#pragma unroll
                for (int r = 0; r < 4; ++r)
                    smem[(wm + mt * 16 + quad * 4 + r) * 136 + wn + nt * 16 + c] =
                        f2bf(acc[mt][nt][r] * scale);
    } else {  // transposed stage: [n][m]
#pragma unroll
        for (int mt = 0; mt < 4; ++mt)
#pragma unroll
            for (int nt = 0; nt < 4; ++nt)
#pragma unroll
                for (int r = 0; r < 4; ++r)
                    smem[(wn + nt * 16 + c) * 136 + wm + mt * 16 + quad * 4 + r] =
                        f2bf(acc[mt][nt][r]);
    }
    __syncthreads();

    int rr = tid >> 4, cc = tid & 15;
    if (!vreg) {
        int col = n0 + cc * 8;
        int which = col >> 10;               // uniform per block (0=Q, 1=K)
        int h = (col >> 6) & 15, d = col & 63;
        unsigned short* dst = which ? kout : qout;
#pragma unroll
        for (int j = 0; j < 8; ++j) {
            int row = rr + j * 16;
            int grow = m0 + row;
            int b = grow >> 11, t = grow & 2047;
            size_t bh_ = (size_t)(b * 16 + h);
            bf16x8 vv = *(const bf16x8*)&smem[row * 136 + cc * 8];
            *(bf16x8*)&dst[(bh_ * 2048 + t) * 64 + d] = vv;
        }
    } else {
        int grow = m0 + cc * 8;
        int b = grow >> 11, t = grow & 2047;  // whole 8-chunk stays in one b,t-range
#pragma unroll
        for (int j = 0; j < 8; ++j) {
            int nrow = rr + j * 16;
            int col = n0 + nrow;
            int h = (col >> 6) & 15, d = col & 63;
            size_t bh_ = (size_t)(b * 16 + h);
            bf16x8 vv = *(const bf16x8*)&smem[nrow * 136 + cc * 8];
            *(bf16x8*)&vtout[(bh_ * 64 + d) * 2048 + t] = vv;
        }
    }
}

// ---- output GEMM: BK=64 swizzled, XCD-chunked, fp32 store ----
__global__ __launch_bounds__(256, 2) void gemm2_bt(
    const unsigned short* __restrict__ A,    // 8192 x 1024 bf16
    const unsigned short* __restrict__ Bt,   // 1024 x 1024 bf16
    float* __restrict__ out) {
    const int K = 1024, N = 1024;
    __shared__ __align__(16) unsigned short sA[128 * 64], sB[128 * 64];
    int tid = threadIdx.x, lane = tid & 63, w = tid >> 6;
    int c = lane & 15, quad = lane >> 4;
    int sw = c & 7;
    int wm = (w >> 1) * 64, wn = (w & 1) * 64;

    // XCD-chunked swizzle: 512 wgs, 64/XCD -> XCD owns 8 m-rows; A-chunk (2MB)
    // + full B (2MB) fit the 4MB XCD L2.
    int wg = blockIdx.y * 8 + blockIdx.x;
    int nid = (wg & 7) * 64 + (wg >> 3);
    int m_blk = nid >> 3, n_blk = nid & 7;
    int m0 = m_blk * 128, n0 = n_blk * 128;

    f32x4 acc[4][4];
#pragma unroll
    for (int i = 0; i < 4; i++)
#pragma unroll
        for (int j = 0; j < 4; j++) acc[i][j] = (f32x4){0.f, 0.f, 0.f, 0.f};

    for (int kk = 0; kk < K; kk += 64) {
#pragma unroll
        for (int p = 0; p < 4; ++p) {
            int ch = p * 256 + tid;
            int r = ch >> 3;
            int gs = (ch & 7) ^ (r & 7);
            gload_lds16(A + (size_t)(m0 + r) * K + kk + gs * 8, &sA[ch * 8]);
            gload_lds16(Bt + (size_t)(n0 + r) * K + kk + gs * 8, &sB[ch * 8]);
        }
        __syncthreads();
#pragma unroll
        for (int ks8 = 0; ks8 < 8; ks8 += 4) {
            bf16x8 af[4], bfr[4];
#pragma unroll
            for (int mt = 0; mt < 4; ++mt)
                af[mt] = *(const bf16x8*)&sA[(wm + mt * 16 + c) * 64 +
                                             ((ks8 + quad) ^ sw) * 8];
#pragma unroll
            for (int nt = 0; nt < 4; ++nt)
                bfr[nt] = *(const bf16x8*)&sB[(wn + nt * 16 + c) * 64 +
                                              ((ks8 + quad) ^ sw) * 8];
#pragma unroll
            for (int mt = 0; mt < 4; ++mt)
#pragma unroll
                for (int nt = 0; nt < 4; ++nt)
                    acc[mt][nt] = MFMA16(af[mt], bfr[nt], acc[mt][nt]);
        }
        __syncthreads();
    }

#pragma unroll
    for (int mt = 0; mt < 4; ++mt)
#pragma unroll
        for (int nt = 0; nt < 4; ++nt)
#pragma unroll
            for (int r = 0; r < 4; ++r) {
                int row = m0 + wm + mt * 16 + quad * 4 + r;
                int col = n0 + wn + nt * 16 + c;
                out[(size_t)row * N + col] = acc[mt][nt][r];
            }
}

// ---- causal flash attention: S^T/O^T, P in regs, NO-MAX softmax ----
// v5: PERSISTENT blocks + dynamic work queue. 1024 blocks (= exact 4/CU
// capacity) loop over a 1536-entry job queue (longest-first) via one
// atomicAdd per job -> self-balancing, no dispatch ramp/tail. Split pieces
// still write their own fp32 scratch slots (atomic-free); merge_k combines.
// P->bf16 pack now uses v_cvt_pk_bf16_f32 (2 ops vs 6).
#define SSTR 72
__device__ const int JOB_ORDER[24] = {7, 15, 23, 14, 22, 6,  13, 21, 12, 20, 5,  11,
                                      19, 10, 18, 4,  9,  17, 8,  16, 3,  2,  1,  0};

__global__ __launch_bounds__(256, 4) void attn_k(
    const unsigned short* __restrict__ q,
    const unsigned short* __restrict__ k,
    const unsigned short* __restrict__ vt,
    unsigned short* __restrict__ ctx,
    float* __restrict__ op, float* __restrict__ lbuf,
    int* __restrict__ counter) {
    const int T = 2048, D = 64;
    __shared__ __align__(16) unsigned short sK[2][64 * SSTR];  // [buf][key][d]
    __shared__ __align__(16) unsigned short sV[2][64 * SSTR];  // [buf][d][key]
    __shared__ int sNext;

    int tid = threadIdx.x, lane = tid & 63, w = tid >> 6;
    int c = lane & 15, quad = lane >> 4;
    int dv = tid >> 3, tcv = (tid & 7) * 8;

    int qi = blockIdx.x;
    while (qi < 1536) {
        // job decode: rank (longest-first) x bh
        int rank = qi >> 6, bh = qi & 63;
        int t = JOB_ORDER[rank];
        int jt, kt0, nkt;
        bool split, has_diag;
        if (t < 8)       { jt = t;     kt0 = 0;      nkt = 2 * t + 2; split = false; has_diag = true; }
        else if (t < 16) { jt = t;     kt0 = 0;      nkt = jt + 1;    split = true;  has_diag = false; }
        else             { jt = t - 8; kt0 = jt + 1; nkt = jt + 1;    split = true;  has_diag = true; }
        int kt_end = kt0 + nkt;
        int b = bh >> 4, hh = bh & 15;

        const unsigned short* qh = q + (size_t)bh * T * D;
        const unsigned short* kh = k + (size_t)bh * T * D;
        const unsigned short* vh = vt + (size_t)bh * D * T;

        int q0 = jt * 128;
        int qloc = w * 16 + c;
        int qrow[2];
        qrow[0] = q0 + qloc;
        qrow[1] = qrow[0] + 64;

        bf16x8 bq[2][2];
#pragma unroll
        for (int g = 0; g < 2; ++g) {
            bq[g][0] = *(const bf16x8*)&qh[(size_t)qrow[g] * D + quad * 8];
            bq[g][1] = *(const bf16x8*)&qh[(size_t)qrow[g] * D + 32 + quad * 8];
        }

        f32x4 o[2][4];
#pragma unroll
        for (int g = 0; g < 2; ++g)
#pragma unroll
            for (int nt = 0; nt < 4; ++nt) o[g][nt] = (f32x4){0.f, 0.f, 0.f, 0.f};
        float l_i[2] = {0.f, 0.f};

        // stage first tile (kt0) into buffer 0
        int kb0 = kt0 * 64;
        bf16x8 kr0 = *(const bf16x8*)&kh[(size_t)(kb0 + lane) * D + w * 8];
        bf16x8 kr1 = *(const bf16x8*)&kh[(size_t)(kb0 + lane) * D + w * 8 + 32];
        bf16x8 vr0 = *(const bf16x8*)&vh[(size_t)dv * T + kb0 + tcv];
        bf16x8 vr1 = *(const bf16x8*)&vh[(size_t)(dv + 32) * T + kb0 + tcv];
        *(bf16x8*)&sK[0][lane * SSTR + w * 8] = kr0;
        *(bf16x8*)&sK[0][lane * SSTR + w * 8 + 32] = kr1;
        *(bf16x8*)&sV[0][dv * SSTR + tcv] = vr0;
        *(bf16x8*)&sV[0][(dv + 32) * SSTR + tcv] = vr1;
        __syncthreads();

        int cur = 0;
        for (int kt = kt0; kt < kt_end; ++kt) {
            int kb = kt * 64;
            if (kt + 1 < kt_end) {  // prefetch next tile into registers
                int kb2 = kb + 64;
                kr0 = *(const bf16x8*)&kh[(size_t)(kb2 + lane) * D + w * 8];
                kr1 = *(const bf16x8*)&kh[(size_t)(kb2 + lane) * D + w * 8 + 32];
                vr0 = *(const bf16x8*)&vh[(size_t)dv * T + kb2 + tcv];
                vr1 = *(const bf16x8*)&vh[(size_t)(dv + 32) * T + kb2 + tcv];
            }
            // last tile of a diag-carrying job is fully masked for group 0
            bool g0_active = !has_diag || (kt != 2 * jt + 1);

            const unsigned short* sKc = sK[cur];
            const unsigned short* sVc = sV[cur];

            // S^T = K · Q^T
            f32x4 st[2][4];
            __builtin_amdgcn_s_setprio(1);
#pragma unroll
            for (int mt = 0; mt < 4; ++mt) {
                bf16x8 ak0 = *(const bf16x8*)&sKc[(mt * 16 + c) * SSTR + quad * 8];
                bf16x8 ak1 = *(const bf16x8*)&sKc[(mt * 16 + c) * SSTR + 32 + quad * 8];
#pragma unroll
                for (int g = 0; g < 2; ++g) {
                    f32x4 z = (f32x4){0.f, 0.f, 0.f, 0.f};
                    z = MFMA16(ak0, bq[g][0], z);
                    z = MFMA16(ak1, bq[g][1], z);
                    st[g][mt] = z;
                }
            }
            __builtin_amdgcn_s_setprio(0);

            // p = exp2(s) directly; pack into PV B-fragments (registers)
            bf16x4 pf[2][4];
#pragma unroll
            for (int g = 0; g < 2; ++g) {
                if (g == 0 && !g0_active) continue;
                bool diag = has_diag && (kb == q0 + (g << 6));
                if (diag) {
#pragma unroll
                    for (int mt = 0; mt < 4; ++mt)
#pragma unroll
                        for (int r = 0; r < 4; ++r)
                            if (mt * 16 + quad * 4 + r > qloc) st[g][mt][r] = -1.0e30f;
                }
                float rs = 0.f;
#pragma unroll
                for (int mt = 0; mt < 4; ++mt) {
                    float p0 = __builtin_exp2f(st[g][mt][0]);
                    float p1 = __builtin_exp2f(st[g][mt][1]);
                    float p2 = __builtin_exp2f(st[g][mt][2]);
                    float p3 = __builtin_exp2f(st[g][mt][3]);
                    rs += (p0 + p1) + (p2 + p3);
                    unsigned int w0, w1;
                    asm("v_cvt_pk_bf16_f32 %0, %1, %2" : "=v"(w0) : "v"(p0), "v"(p1));
                    asm("v_cvt_pk_bf16_f32 %0, %1, %2" : "=v"(w1) : "v"(p2), "v"(p3));
                    uint2 pk; pk.x = w0; pk.y = w1;
                    pf[g][mt] = *(bf16x4*)&pk;
                }
                l_i[g] += rs;
            }

            // O^T += V^T · P^T  via 16x16x16 MFMA (B-operand straight from regs)
            __builtin_amdgcn_s_setprio(1);
#pragma unroll
            for (int mt = 0; mt < 4; ++mt) {
#pragma unroll
                for (int nt = 0; nt < 4; ++nt) {
                    bf16x4 av = *(const bf16x4*)&sVc[(nt * 16 + c) * SSTR + mt * 16 + quad * 4];
                    if (g0_active) o[0][nt] = MFMA16K16(av, pf[0][mt], o[0][nt]);
                    o[1][nt] = MFMA16K16(av, pf[1][mt], o[1][nt]);
                }
            }
            __builtin_amdgcn_s_setprio(0);

            if (kt + 1 < kt_end) {  // commit prefetched tile to the other buffer
                int nxt = cur ^ 1;
                *(bf16x8*)&sK[nxt][lane * SSTR + w * 8] = kr0;
                *(bf16x8*)&sK[nxt][lane * SSTR + w * 8 + 32] = kr1;
                *(bf16x8*)&sV[nxt][dv * SSTR + tcv] = vr0;
                *(bf16x8*)&sV[nxt][(dv + 32) * SSTR + tcv] = vr1;
                __syncthreads();
                cur = nxt;
            }
        }

        // grab next job early; atomic latency hides under the epilogue stores
        if (tid == 0) sNext = atomicAdd(counter, 1);

        if (!split) {
            // epilogue: cross-lane l reduction, normalized bf16 store
#pragma unroll
            for (int g = 0; g < 2; ++g) {
                float l = l_i[g];
                l += __shfl_xor(l, 16);
                l += __shfl_xor(l, 32);
                float inv = 1.0f / l;
#pragma unroll
                for (int nt = 0; nt < 4; ++nt) {
                    u16x4 ob;
#pragma unroll
                    for (int r = 0; r < 4; ++r) ob[r] = f2bf(o[g][nt][r] * inv);
                    *(u16x4*)&ctx[(size_t)(b * T + qrow[g]) * 1024 + hh * 64 + nt * 16 + quad * 4] = ob;
                }
            }
        } else {
            // partial epilogue: plain coalesced fp32 stores into this piece's slot
            int piece = has_diag ? 1 : 0;
            int sidx = bh * 8 + (jt - 8);
            size_t base = (size_t)(piece * 512 + sidx) * 128;
#pragma unroll
            for (int g = 0; g < 2; ++g) {
                float l = l_i[g];
                l += __shfl_xor(l, 16);
                l += __shfl_xor(l, 32);
                int rloc = qrow[g] - q0;
                if (quad == 0) lbuf[base + rloc] = l;
                float* orow = op + (base + rloc) * 64;
#pragma unroll
                for (int nt = 0; nt < 4; ++nt)
                    *(f32x4*)&orow[nt * 16 + quad * 4] = o[g][nt];
            }
        }

        __syncthreads();  // LDS reuse + sNext visibility
        qi = sNext;
    }
}

// ---- combine the two pieces of each split job, normalize, write bf16 ctx ----
__global__ void merge_k(const float* __restrict__ op, const float* __restrict__ lbuf,
                        unsigned short* __restrict__ ctx) {
    int gid = blockIdx.x * 256 + threadIdx.x;  // 512*128*16 = 1,048,576
    int row = gid >> 4, dq = (gid & 15) * 4;
    int sidx = row >> 7, rloc = row & 127;
    int bh = sidx >> 3, jt = 8 + (sidx & 7);
    int b = bh >> 4, hh = bh & 15;
    int tq = jt * 128 + rloc;
    float inv = 1.0f / (lbuf[row] + lbuf[65536 + row]);
    float4 o0 = *(const float4*)(op + (size_t)row * 64 + dq);
    float4 o1 = *(const float4*)(op + (size_t)(65536 + row) * 64 + dq);
    u16x4 ob;
    ob[0] = f2bf((o0.x + o1.x) * inv);
    ob[1] = f2bf((o0.y + o1.y) * inv);
    ob[2] = f2bf((o0.z + o1.z) * inv);
    ob[3] = f2bf((o0.w + o1.w) * inv);
    *(u16x4*)&ctx[((size_t)(b * 2048 + tq)) * 1024 + hh * 64 + dq] = ob;
}

extern "C" void kernel_launch(void* const* d_in, const int* in_sizes, int n_in,
                              void* d_out, int out_size, void* d_ws, size_t ws_size,
                              hipStream_t stream) {
    const float* x     = (const float*)d_in[0];  // (4,2048,1024) fp32
    const float* w_qkv = (const float*)d_in[1];  // (1024,3072) fp32
    const float* w_out = (const float*)d_in[2];  // (1024,1024) fp32
    float* out = (float*)d_out;                  // (4,2048,1024) fp32

    char* ws = (char*)d_ws;
    unsigned short* wqkvt = (unsigned short*)(ws + 0);          //  6.29 MB
    unsigned short* woutt = (unsigned short*)(ws + 6291456);    //  2.10 MB
    unsigned short* x_bf  = (unsigned short*)(ws + 8388608);    // 16.78 MB
    unsigned short* qb    = (unsigned short*)(ws + 25165824);   // 16.78 MB
    unsigned short* kb    = (unsigned short*)(ws + 41943040);   // 16.78 MB
    unsigned short* vtb   = (unsigned short*)(ws + 58720256);   // 16.78 MB
    unsigned short* ctx   = (unsigned short*)(ws + 8388608);    // reuse x_bf slot

    // split-piece scratch (all dead-after-use regions):
    //   op[2][512][128][64] f32 = 33.55 MB -> d_out (dead until gemm2 writes it)
    //   lbuf[2][512][128]  f32 = 512 KB   -> ws[0, 512K)      (wqkvt slot)
    //   counter            int           -> ws + 524288       (wqkvt slot)
    float* op    = (float*)d_out;
    float* lbuf  = (float*)ws;
    int* counter = (int*)(ws + 524288);

    cast_x<<<8192, 256, 0, stream>>>(x, x_bf, 8388608);
    tcast_k<<<dim3(48, 16), 256, 0, stream>>>(w_qkv, wqkvt, 1024, 3072);
    tcast_k<<<dim3(16, 16), 256, 0, stream>>>(w_out, woutt, 1024, 1024);
    gemm_qkv<<<dim3(24, 64), 256, 0, stream>>>(x_bf, wqkvt, qb, kb, vtb, counter);
    attn_k<<<1024, 256, 0, stream>>>(qb, kb, vtb, ctx, op, lbuf, counter);
    merge_k<<<4096, 256, 0, stream>>>(op, lbuf, ctx);
    gemm2_bt<<<dim3(8, 64), 256, 0, stream>>>(ctx, woutt, out);
}